// Round 4
// baseline (198.876 us; speedup 1.0000x reference)
//
#include <hip/hip_runtime.h>

#define BINS 256
#define HWPIX (512 * 512)        // pixels per channel
#define NCH 192                  // B*C = 64*3
#define TPB 1024                 // one block handles one whole channel
#define VPT (HWPIX / 4 / TPB)    // 64 float4 per thread = 256 px/thread

// Fully fused per-channel equalize: one block = one channel.
// Phase 1: read fp32 once, quantize, LDS histogram, keep u8 bins packed in
//          64 VGPRs/thread.
// Phase 2: block-local LUT (last-nonzero reduce + inclusive scan), bit-exact
//          with the reference; LUT pre-divided by 255.
// Phase 3: gather from LDS LUT, write fp32 once.
// No workspace, no global atomics, no grid sync, single dispatch.
__global__ __launch_bounds__(TPB, 4) void equalize_onepass(const float* __restrict__ x,
                                                           float* __restrict__ out) {
    __shared__ int   h[BINS];
    __shared__ int   cum[BINS];
    __shared__ int   red[BINS];
    __shared__ float lutf[BINS];

    const int t  = threadIdx.x;
    const int ch = blockIdx.x;

    if (t < BINS) h[t] = 0;
    __syncthreads();

    const size_t base = (size_t)ch * HWPIX;
    const float4* in4  = (const float4*)(x + base);
    float4*       out4 = (float4*)(out + base);

    unsigned int packed[VPT];   // fully unrolled -> static indices -> registers

    // ---- Phase 1: load + quantize + LDS histogram ----
#pragma unroll
    for (int i = 0; i < VPT; ++i) {
        float4 v = in4[t + i * TPB];
        int b0 = (int)fminf(fmaxf(floorf(v.x * 255.0f), 0.0f), 255.0f);
        int b1 = (int)fminf(fmaxf(floorf(v.y * 255.0f), 0.0f), 255.0f);
        int b2 = (int)fminf(fmaxf(floorf(v.z * 255.0f), 0.0f), 255.0f);
        int b3 = (int)fminf(fmaxf(floorf(v.w * 255.0f), 0.0f), 255.0f);
        packed[i] = (unsigned int)b0 | ((unsigned int)b1 << 8) |
                    ((unsigned int)b2 << 16) | ((unsigned int)b3 << 24);
        atomicAdd(&h[b0], 1);
        atomicAdd(&h[b1], 1);
        atomicAdd(&h[b2], 1);
        atomicAdd(&h[b3], 1);
    }
    __syncthreads();

    // ---- Phase 2: LUT (threads 0..255 do the 256-bin work) ----
    if (t < BINS) {
        const int hv = h[t];
        cum[t] = hv;
        red[t] = (hv > 0) ? t : -1;
    }
    __syncthreads();

    for (int off = 128; off > 0; off >>= 1) {       // last nonzero bin index
        if (t < off) red[t] = max(red[t], red[t + off]);
        __syncthreads();
    }
    for (int off = 1; off < BINS; off <<= 1) {      // inclusive scan (Hillis-Steele)
        int v = 0, a = 0;
        if (t < BINS) {
            v = cum[t];
            a = (t >= off) ? cum[t - off] : 0;
        }
        __syncthreads();
        if (t < BINS) cum[t] = v + a;
        __syncthreads();
    }

    if (t < BINS) {
        const int last = h[red[0]];
        const int step = (HWPIX - last) / 255;
        int lutv;
        if (step == 0) {
            lutv = t;                               // identity channel
        } else if (t == 0) {
            lutv = 0;                               // shifted-right-by-one head
        } else {
            int val = (cum[t - 1] + (step >> 1)) / step;
            lutv = min(max(val, 0), 255);
        }
        lutf[t] = (float)lutv / 255.0f;             // pre-divide (bit-exact w/ ref)
    }
    __syncthreads();

    // ---- Phase 3: apply from registers ----
#pragma unroll
    for (int i = 0; i < VPT; ++i) {
        const unsigned int p = packed[i];
        float4 o;
        o.x = lutf[p & 255u];
        o.y = lutf[(p >> 8) & 255u];
        o.z = lutf[(p >> 16) & 255u];
        o.w = lutf[p >> 24];
        out4[t + i * TPB] = o;
    }
}

extern "C" void kernel_launch(void* const* d_in, const int* in_sizes, int n_in,
                              void* d_out, int out_size, void* d_ws, size_t ws_size,
                              hipStream_t stream) {
    const float* x = (const float*)d_in[0];
    float* out = (float*)d_out;
    equalize_onepass<<<NCH, TPB, 0, stream>>>(x, out);
}

// Round 5
// 92.273 us; speedup vs baseline: 2.1553x; 2.1553x over previous
//
#include <hip/hip_runtime.h>

#define BINS 256
#define HWPIX (512 * 512)     // pixels per channel
#define NCH 192               // B*C = 64*3
#define BPC 32                // blocks per channel
#define NBLK (NCH * BPC)      // 6144 blocks
// per block: 256 threads x 8 float4 = 8192 px; 32 blocks = 262144 = HWPIX

// Workspace: [ partial hists: NBLK*BINS int ][ staged u8 (as u32): NCH*HWPIX/4 ]
#define PWS_BYTES ((size_t)NBLK * BINS * sizeof(int))

typedef float f4v __attribute__((ext_vector_type(4)));

// ---------------- Dispatch A: histogram (non-atomic partials) + stage u8 ----------------
__global__ __launch_bounds__(256) void hist_stage(const float* __restrict__ x,
                                                  int* __restrict__ pws,
                                                  unsigned int* __restrict__ staged) {
    __shared__ int h[BINS];
    const int t = threadIdx.x;
    h[t] = 0;
    __syncthreads();

    const int ch  = blockIdx.x >> 5;
    const int blk = blockIdx.x & 31;
    const f4v* in4 = (const f4v*)(x + (size_t)ch * HWPIX);
    unsigned int* st = staged + (size_t)ch * (HWPIX / 4);
    const int idx0 = blk * 2048 + t;

#pragma unroll
    for (int i = 0; i < 8; ++i) {
        const int k = idx0 + i * 256;
        f4v v = __builtin_nontemporal_load(&in4[k]);   // input read exactly once
        int b0 = (int)fminf(fmaxf(floorf(v.x * 255.0f), 0.0f), 255.0f);
        int b1 = (int)fminf(fmaxf(floorf(v.y * 255.0f), 0.0f), 255.0f);
        int b2 = (int)fminf(fmaxf(floorf(v.z * 255.0f), 0.0f), 255.0f);
        int b3 = (int)fminf(fmaxf(floorf(v.w * 255.0f), 0.0f), 255.0f);
        st[k] = (unsigned int)b0 | ((unsigned int)b1 << 8) |
                ((unsigned int)b2 << 16) | ((unsigned int)b3 << 24);   // cached: re-read in B
        atomicAdd(&h[b0], 1);
        atomicAdd(&h[b1], 1);
        atomicAdd(&h[b2], 1);
        atomicAdd(&h[b3], 1);
    }
    __syncthreads();
    pws[(size_t)blockIdx.x * BINS + t] = h[t];         // non-atomic, coalesced
}

// ---------------- Dispatch B: reduce partials + per-block LUT + apply ----------------
__global__ __launch_bounds__(256) void lut_apply(const int* __restrict__ pws,
                                                 const unsigned int* __restrict__ staged,
                                                 float* __restrict__ out) {
    __shared__ int   h[BINS];
    __shared__ int   cum[BINS];
    __shared__ int   red[BINS];
    __shared__ float lutf[BINS];

    const int t = threadIdx.x;
    const int ch  = blockIdx.x >> 5;
    const int blk = blockIdx.x & 31;

    // reduce the channel's 32 partial histograms (L2/L3-hot, coalesced)
    const int* base = pws + (size_t)ch * BPC * BINS;
    int s = 0;
#pragma unroll
    for (int b = 0; b < BPC; ++b) s += base[b * BINS + t];
    h[t]   = s;
    cum[t] = s;
    red[t] = (s > 0) ? t : -1;
    __syncthreads();

    for (int off = 128; off > 0; off >>= 1) {          // last nonzero bin index
        if (t < off) red[t] = max(red[t], red[t + off]);
        __syncthreads();
    }
    for (int off = 1; off < BINS; off <<= 1) {         // inclusive scan
        int v = cum[t];
        int a = (t >= off) ? cum[t - off] : 0;
        __syncthreads();
        cum[t] = v + a;
        __syncthreads();
    }

    const int last = h[red[0]];
    const int step = (HWPIX - last) / 255;
    int lutv;
    if (step == 0) {
        lutv = t;                                      // identity channel
    } else if (t == 0) {
        lutv = 0;                                      // shifted-right-by-one head
    } else {
        int val = (cum[t - 1] + (step >> 1)) / step;
        lutv = min(max(val, 0), 255);
    }
    lutf[t] = (float)lutv / 255.0f;                    // pre-divide (bit-exact w/ ref)
    __syncthreads();

    // apply from staged u8 (L3-resident), write output nontemporal (never re-read)
    const unsigned int* st = staged + (size_t)ch * (HWPIX / 4);
    f4v* out4 = (f4v*)(out + (size_t)ch * HWPIX);
    const int idx0 = blk * 2048 + t;

#pragma unroll
    for (int i = 0; i < 8; ++i) {
        const int k = idx0 + i * 256;
        const unsigned int p = st[k];
        f4v o;
        o.x = lutf[p & 255u];
        o.y = lutf[(p >> 8) & 255u];
        o.z = lutf[(p >> 16) & 255u];
        o.w = lutf[p >> 24];
        __builtin_nontemporal_store(o, &out4[k]);
    }
}

extern "C" void kernel_launch(void* const* d_in, const int* in_sizes, int n_in,
                              void* d_out, int out_size, void* d_ws, size_t ws_size,
                              hipStream_t stream) {
    const float* x = (const float*)d_in[0];
    float* out = (float*)d_out;

    int* pws = (int*)d_ws;
    unsigned int* staged = (unsigned int*)((char*)d_ws + PWS_BYTES);

    hist_stage<<<NBLK, 256, 0, stream>>>(x, pws, staged);
    lut_apply <<<NBLK, 256, 0, stream>>>(pws, staged, out);
}